// Round 7
// baseline (30.210 us; speedup 1.0000x reference)
//
#include <hip/hip_runtime.h>

#define B_ 32
#define PHONE_LEN_ 600
#define T_ 4096
#define H_ 256
#define TPB_ 256   // t's per block (4 waves x 64 t)

typedef float vfloat4 __attribute__((ext_vector_type(4)));

// Single fused kernel, R6 winner scaled up:
//  - TPB 128->256 (512 blocks: halves prologue count; 2 blocks/CU resident)
//  - full-wave scalar preload: reg_iv/reg_p/reg_b each cover the wave's 64
//    t's across all 64 lanes (no half-wave branch); main loop readlanes all
//    three -> iv/pv/bv wave-uniform, enc address = scalar base + lane*16.
//  - non-temporal out stores (proven win R5 A/B).
//
// idx per block without a t-scan, exploiting sorted align rows:
// idx[t] = (#present values < align[t]) + (align[0]!=0).
__global__ __launch_bounds__(256) void fuse_kernel(
    const float* __restrict__ enc,    // [B, PHONE_LEN, H]
    const float* __restrict__ pitch,  // [B, T]
    const float* __restrict__ beats,  // [B, T]
    const float* __restrict__ wp, const float* __restrict__ bp,
    const float* __restrict__ wb, const float* __restrict__ bb,
    const float* __restrict__ ws, const float* __restrict__ bs,
    const int* __restrict__ align,    // [B, T] (sorted per row)
    float* __restrict__ out) {        // [B, T, H]
    const int tid  = threadIdx.x;
    const int lane = tid & 63;
    const int warp = tid >> 6;                // 0..3
    const int b  = blockIdx.y;
    const int t0 = blockIdx.x * TPB_;

    __shared__ unsigned char pres[512];
    __shared__ int pref[512];
    __shared__ int wsum[4];

    const int* __restrict__ arow = align + (size_t)b * T_;

    // ---- presence bitmap over the whole row (4096 elems, 16 per thread) ----
    reinterpret_cast<unsigned short*>(pres)[tid] = 0;
    __syncthreads();
#pragma unroll
    for (int i = 0; i < 16; i += 4) {
        int4 v = *reinterpret_cast<const int4*>(arow + tid * 16 + i);
        pres[v.x] = 1; pres[v.y] = 1; pres[v.z] = 1; pres[v.w] = 1;
    }
    __syncthreads();

    // ---- block-wide exclusive prefix sum of presence (2 entries/thread) ----
    const int p0 = pres[2 * tid];
    const int p1 = pres[2 * tid + 1];
    const int s  = p0 + p1;
    int scan = s;
#pragma unroll
    for (int off = 1; off < 64; off <<= 1) {
        int n = __shfl_up(scan, off, 64);
        if (lane >= off) scan += n;
    }
    if (lane == 63) wsum[warp] = scan;
    __syncthreads();
    int woff = 0;
#pragma unroll
    for (int w = 0; w < 4; ++w) woff += (w < warp) ? wsum[w] : 0;
    const int excl = woff + scan - s;         // #present values < 2*tid
    pref[2 * tid]     = excl;
    pref[2 * tid + 1] = excl + p0;
    __syncthreads();

    const int adj = (arow[0] != 0) ? 1 : 0;

    // ---- full-wave scalar preload: 64 t's per wave ----
    const int tw = t0 + warp * 64;
    const size_t btw = (size_t)b * T_ + tw;

    const int   reg_iv = pref[arow[tw + lane]] + adj;
    const int   reg_p  = __float_as_int(pitch[btw + lane]);
    const int   reg_b  = __float_as_int(beats[btw + lane]);

    // ---- weights / fused bias ----
    const int h4 = lane * 4;
    const float4 w_p = *reinterpret_cast<const float4*>(wp + h4);
    const float4 w_b = *reinterpret_cast<const float4*>(wb + h4);
    const float4 w_s = *reinterpret_cast<const float4*>(ws + h4);
    float4 bsum;
    {
        const float4 b1 = *reinterpret_cast<const float4*>(bp + h4);
        const float4 b2 = *reinterpret_cast<const float4*>(bb + h4);
        const float4 b3 = *reinterpret_cast<const float4*>(bs + h4);
        bsum.x = b1.x + b2.x + b3.x;
        bsum.y = b1.y + b2.y + b3.y;
        bsum.z = b1.z + b2.z + b3.z;
        bsum.w = b1.w + b2.w + b3.w;
    }

    const float invT = 1.0f / (float)T_;
    const float* encb = enc + (size_t)b * PHONE_LEN_ * H_;
    float* outb = out + btw * H_;

#pragma unroll
    for (int i = 0; i < 64; ++i) {
        const int   iv = __builtin_amdgcn_readlane(reg_iv, i);       // SGPR
        const float pv = __int_as_float(__builtin_amdgcn_readlane(reg_p, i));
        const float bv = __int_as_float(__builtin_amdgcn_readlane(reg_b, i));
        const float psc = (float)(tw + i) * invT;

        const float4 e = *reinterpret_cast<const float4*>(encb + iv * H_ + h4);

        vfloat4 r;
        r.x = e.x + pv * w_p.x + bv * w_b.x + psc * w_s.x + bsum.x;
        r.y = e.y + pv * w_p.y + bv * w_b.y + psc * w_s.y + bsum.y;
        r.z = e.z + pv * w_p.z + bv * w_b.z + psc * w_s.z + bsum.z;
        r.w = e.w + pv * w_p.w + bv * w_b.w + psc * w_s.w + bsum.w;

        __builtin_nontemporal_store(r, reinterpret_cast<vfloat4*>(outb + i * H_ + h4));
    }
}

extern "C" void kernel_launch(void* const* d_in, const int* in_sizes, int n_in,
                              void* d_out, int out_size, void* d_ws, size_t ws_size,
                              hipStream_t stream) {
    const float* enc   = (const float*)d_in[0];
    const float* pitch = (const float*)d_in[1];
    const float* beats = (const float*)d_in[2];
    const float* wp    = (const float*)d_in[3];
    const float* bp    = (const float*)d_in[4];
    const float* wb    = (const float*)d_in[5];
    const float* bb    = (const float*)d_in[6];
    const float* wsp   = (const float*)d_in[7];
    const float* bsp   = (const float*)d_in[8];
    const int*   align = (const int*)d_in[9];

    fuse_kernel<<<dim3(T_ / TPB_, B_), 256, 0, stream>>>(
        enc, pitch, beats, wp, bp, wb, bb, wsp, bsp, align, (float*)d_out);
}

// Round 8
// 28.199 us; speedup vs baseline: 1.0713x; 1.0713x over previous
//
#include <hip/hip_runtime.h>

#define B_ 32
#define PHONE_LEN_ 600
#define T_ 4096
#define H_ 256
#define TPB_ 128   // t's per block (4 waves x 32 t) — R6 empirical optimum

typedef float vfloat4 __attribute__((ext_vector_type(4)));

// R6 winner (28.3 us), reverted after TPB=256 regression in R7.
//  - single fused kernel: per-block idx reconstruction (sorted align ->
//    presence bitmap + block prefix sum), no scan kernel, no d_ws.
//  - per-wave scalar preload: lanes 0..31 hold {idx,pitch}, lanes 32..63
//    hold beats for the wave's 32 t's; main loop readlanes -> iv/pv/bv are
//    wave-uniform SGPRs, enc address = scalar base + lane*16.
//  - non-temporal out stores (isolated +1.6 us win in R5).
// Empirical neighborhood: TPB=64 (-2 us), TPB=256 (-1.9 us), XCD swizzle
// (-2.5 us), no-NT (-1.6 us) — all worse.
__global__ __launch_bounds__(256) void fuse_kernel(
    const float* __restrict__ enc,    // [B, PHONE_LEN, H]
    const float* __restrict__ pitch,  // [B, T]
    const float* __restrict__ beats,  // [B, T]
    const float* __restrict__ wp, const float* __restrict__ bp,
    const float* __restrict__ wb, const float* __restrict__ bb,
    const float* __restrict__ ws, const float* __restrict__ bs,
    const int* __restrict__ align,    // [B, T] (sorted per row)
    float* __restrict__ out) {        // [B, T, H]
    const int tid  = threadIdx.x;
    const int lane = tid & 63;
    const int warp = tid >> 6;                // 0..3
    const int b  = blockIdx.y;
    const int t0 = blockIdx.x * TPB_;

    __shared__ unsigned char pres[512];
    __shared__ int pref[512];
    __shared__ int wsum[4];

    const int* __restrict__ arow = align + (size_t)b * T_;

    // ---- presence bitmap over the whole row (4096 elems, 16 per thread) ----
    reinterpret_cast<unsigned short*>(pres)[tid] = 0;
    __syncthreads();
#pragma unroll
    for (int i = 0; i < 16; i += 4) {
        int4 v = *reinterpret_cast<const int4*>(arow + tid * 16 + i);
        pres[v.x] = 1; pres[v.y] = 1; pres[v.z] = 1; pres[v.w] = 1;
    }
    __syncthreads();

    // ---- block-wide exclusive prefix sum of presence (2 entries/thread) ----
    const int p0 = pres[2 * tid];
    const int p1 = pres[2 * tid + 1];
    const int s  = p0 + p1;
    int scan = s;
#pragma unroll
    for (int off = 1; off < 64; off <<= 1) {
        int n = __shfl_up(scan, off, 64);
        if (lane >= off) scan += n;
    }
    if (lane == 63) wsum[warp] = scan;
    __syncthreads();
    int woff = 0;
#pragma unroll
    for (int w = 0; w < 4; ++w) woff += (w < warp) ? wsum[w] : 0;
    const int excl = woff + scan - s;         // #present values < 2*tid
    pref[2 * tid]     = excl;
    pref[2 * tid + 1] = excl + p0;
    __syncthreads();

    const int adj = (arow[0] != 0) ? 1 : 0;

    // ---- per-wave scalar preload ----
    // wave handles t in [tw, tw+32); lane<32: idx & pitch for t=tw+lane,
    // lane>=32: beats for t=tw+lane-32.
    const int tw = t0 + warp * 32;
    const size_t btw = (size_t)b * T_ + tw;

    int   reg_iv;
    float reg_pb;
    if (lane < 32) {
        reg_iv = pref[arow[tw + lane]] + adj;
        reg_pb = pitch[btw + lane];
    } else {
        reg_iv = 0;
        reg_pb = beats[btw + (lane - 32)];
    }

    // ---- weights / fused bias ----
    const int h4 = lane * 4;
    const float4 w_p = *reinterpret_cast<const float4*>(wp + h4);
    const float4 w_b = *reinterpret_cast<const float4*>(wb + h4);
    const float4 w_s = *reinterpret_cast<const float4*>(ws + h4);
    float4 bsum;
    {
        const float4 b1 = *reinterpret_cast<const float4*>(bp + h4);
        const float4 b2 = *reinterpret_cast<const float4*>(bb + h4);
        const float4 b3 = *reinterpret_cast<const float4*>(bs + h4);
        bsum.x = b1.x + b2.x + b3.x;
        bsum.y = b1.y + b2.y + b3.y;
        bsum.z = b1.z + b2.z + b3.z;
        bsum.w = b1.w + b2.w + b3.w;
    }

    const float invT = 1.0f / (float)T_;
    const float* encb = enc + (size_t)b * PHONE_LEN_ * H_;
    float* outb = out + (btw)*H_;

    const int ipb = __float_as_int(reg_pb);
#pragma unroll
    for (int i = 0; i < 32; ++i) {
        const int   iv = __builtin_amdgcn_readlane(reg_iv, i);       // SGPR
        const float pv = __int_as_float(__builtin_amdgcn_readlane(ipb, i));
        const float bv = __int_as_float(__builtin_amdgcn_readlane(ipb, 32 + i));
        const float psc = (float)(tw + i) * invT;

        const float4 e = *reinterpret_cast<const float4*>(encb + iv * H_ + h4);

        vfloat4 r;
        r.x = e.x + pv * w_p.x + bv * w_b.x + psc * w_s.x + bsum.x;
        r.y = e.y + pv * w_p.y + bv * w_b.y + psc * w_s.y + bsum.y;
        r.z = e.z + pv * w_p.z + bv * w_b.z + psc * w_s.z + bsum.z;
        r.w = e.w + pv * w_p.w + bv * w_b.w + psc * w_s.w + bsum.w;

        __builtin_nontemporal_store(r, reinterpret_cast<vfloat4*>(outb + i * H_ + h4));
    }
}

extern "C" void kernel_launch(void* const* d_in, const int* in_sizes, int n_in,
                              void* d_out, int out_size, void* d_ws, size_t ws_size,
                              hipStream_t stream) {
    const float* enc   = (const float*)d_in[0];
    const float* pitch = (const float*)d_in[1];
    const float* beats = (const float*)d_in[2];
    const float* wp    = (const float*)d_in[3];
    const float* bp    = (const float*)d_in[4];
    const float* wb    = (const float*)d_in[5];
    const float* bb    = (const float*)d_in[6];
    const float* wsp   = (const float*)d_in[7];
    const float* bsp   = (const float*)d_in[8];
    const int*   align = (const int*)d_in[9];

    fuse_kernel<<<dim3(T_ / TPB_, B_), 256, 0, stream>>>(
        enc, pitch, beats, wp, bp, wb, bb, wsp, bsp, align, (float*)d_out);
}